// Round 1
// baseline (572.851 us; speedup 1.0000x reference)
//
#include <hip/hip_runtime.h>

#define KD    512
#define NCLS  100000
#define BC    64
#define NB    ((NCLS + BC - 1) / BC)   // 1563
#define R1B   64                       // stage-1 reduce blocks
#define R1C   25                       // strips per stage-1 block (64*25 >= 1563)
#define S_SCALE 64.0f
#define COS_M   0.87758256189037276f
#define SIN_M   0.47942553860420301f
#define THRESH (-0.87758256189037276f)
#define MM_C    0.23971276930210151f

typedef __attribute__((ext_vector_type(8))) short short8;
typedef __attribute__((ext_vector_type(4))) float f32x4;

union Pack8 { unsigned short u[8]; uint4 v; };

__device__ __forceinline__ unsigned short f2bf(float x) {
  unsigned int u = __float_as_uint(x);
  u += 0x7fffu + ((u >> 16) & 1u);   // round-to-nearest-even
  return (unsigned short)(u >> 16);
}

// ---- K0: fused row-normalize(e) -> eb bf16, plus per-row target logit ------
__global__ void k0_norm_target(const float* __restrict__ emb, const float* __restrict__ w,
                               const int* __restrict__ label,
                               unsigned short* __restrict__ eb, float* __restrict__ tlA) {
  int r = blockIdx.x;
  int l = threadIdx.x;                 // 64 lanes, 8 elems each
  const float* src = emb + (size_t)r * KD + l * 8;
  float v[8];
  float ss = 0.f;
#pragma unroll
  for (int j = 0; j < 8; ++j) { v[j] = src[j]; ss += v[j] * v[j]; }
#pragma unroll
  for (int m = 1; m < 64; m <<= 1) ss += __shfl_xor(ss, m, 64);
  float rn = rsqrtf(ss);
  Pack8 p;
#pragma unroll
  for (int j = 0; j < 8; ++j) {
    float x = v[j] * rn;
    v[j] = x;                          // normalized fp32 kept in regs
    p.u[j] = f2bf(x);
  }
  *reinterpret_cast<uint4*>(eb + (size_t)r * KD + l * 8) = p.v;

  // target-column dot + its own norm (fp32 path, matches reference gather)
  int lab = label[r];
  float wv[8];
#pragma unroll
  for (int j = 0; j < 8; ++j) wv[j] = w[(size_t)(l * 8 + j) * NCLS + lab];
  float dot = 0.f, sq = 0.f;
#pragma unroll
  for (int j = 0; j < 8; ++j) { dot += v[j] * wv[j]; sq += wv[j] * wv[j]; }
#pragma unroll
  for (int m = 1; m < 64; m <<= 1) {
    dot += __shfl_xor(dot, m, 64);
    sq  += __shfl_xor(sq, m, 64);
  }
  if (l == 0) {
    float tl = dot * rsqrtf(sq);
    tlA[r] = fminf(1.f, fmaxf(-1.f, tl));
  }
}

// ---- K1: t = 0.01*mean(tl); per-row ctm / final ----------------------------
__global__ void k_prep(const float* __restrict__ tlA, float* __restrict__ ctmA,
                       float* __restrict__ finA, float* __restrict__ tval) {
  __shared__ float red[512];
  int i = threadIdx.x;
  float tl = tlA[i];
  red[i] = tl;
  __syncthreads();
  for (int s = 256; s > 0; s >>= 1) {
    if (i < s) red[i] += red[i + s];
    __syncthreads();
  }
  float st = sqrtf(fmaxf(0.f, 1.f - tl * tl));
  float ctm = tl * COS_M - st * SIN_M;
  ctmA[i] = ctm;
  finA[i] = (tl > THRESH) ? ctm : (tl - MM_C);
  if (i == 0) tval[0] = 0.01f * red[0] * (1.f / 512.f);
}

// ---- K2: bf16 MFMA GEMM (raw w) + epilogue colnorm + row partial sums ------
// Block: 512 rows x 64 cols, K=512. Staging coalesced along c (col = lane),
// two-phase with a binding sched_barrier so all 64 loads of a phase are in
// flight before any pack consumes them (fetch-concurrency fix the compiler
// cannot undo). w loads are nontemporal (read-exactly-once stream).
// LDS B-tile [c][k] swizzled: granule G = c*64 + ((k>>3) ^ (c&7)), 8 bf16/granule.
__global__ __launch_bounds__(256, 2)
void k_gemm(const float* __restrict__ w, const unsigned short* __restrict__ eb,
            const int* __restrict__ label, const float* __restrict__ ctmA,
            const float* __restrict__ finA, const float* __restrict__ tval,
            float2* __restrict__ part) {
  __shared__ __align__(16) unsigned short Bs[BC * KD];   // 64 KB
  __shared__ float ssW[4][BC];
  __shared__ float invnS[BC];
  __shared__ float sE[512];
  __shared__ float sL[512];
  const int tid = threadIdx.x;
  const int wv = tid >> 6;             // wave 0..3
  const int l  = tid & 63;
  const int c0 = blockIdx.x * BC;

  // ---- staging: col = lane; wave wv covers k in {wv*8 + o*32 + j} ----------
  {
    const int c = l;
    const int cgc = (c0 + c < NCLS) ? (c0 + c) : (NCLS - 1);   // clamp, no OOB
    const float* wp = w + cgc;
    float ss = 0.f;
#pragma unroll 1
    for (int ph = 0; ph < 2; ++ph) {
      float vb[8][8];
      // phase issue: 64 independent nontemporal loads, kept together by fence
#pragma unroll
      for (int b = 0; b < 8; ++b) {
        const int kb = wv * 8 + (ph * 8 + b) * 32;
#pragma unroll
        for (int j = 0; j < 8; ++j)
          vb[b][j] = __builtin_nontemporal_load(&wp[(size_t)(kb + j) * NCLS]);
      }
      __builtin_amdgcn_sched_barrier(0);   // nothing crosses: 64 loads stay in flight
      // phase consume: pack + swizzled ds_write_b128
#pragma unroll
      for (int b = 0; b < 8; ++b) {
        const int kb = wv * 8 + (ph * 8 + b) * 32;
        Pack8 p;
#pragma unroll
        for (int j = 0; j < 8; ++j) {
          float x = vb[b][j];
          ss += x * x;
          p.u[j] = f2bf(x);
        }
        const int G = c * 64 + ((kb >> 3) ^ (c & 7));
        *reinterpret_cast<uint4*>(&Bs[G * 8]) = p.v;
      }
    }
    ssW[wv][c] = ss;
  }
  __syncthreads();
  if (tid < BC) {
    float s = ssW[0][tid] + ssW[1][tid] + ssW[2][tid] + ssW[3][tid];
    invnS[tid] = (s > 0.f) ? rsqrtf(s) : 0.f;
  }
  __syncthreads();

  // ---- MFMA main loop: wave tile = 128 rows x 64 cols ----
  const int q  = l >> 4;
  const int cl = l & 15;
  const int rbase = wv * 128;
  f32x4 acc[8][4] = {};

#pragma unroll 1
  for (int s = 0; s < 16; ++s) {
    const int k0 = s * 32 + q * 8;
    short8 a[8], b[4];
#pragma unroll
    for (int ct = 0; ct < 4; ++ct) {
      int c = ct * 16 + cl;
      int G = c * 64 + ((k0 >> 3) ^ (c & 7));
      b[ct] = *reinterpret_cast<const short8*>(&Bs[G * 8]);
    }
#pragma unroll
    for (int rt = 0; rt < 8; ++rt) {
      int row = rbase + rt * 16 + cl;
      a[rt] = *reinterpret_cast<const short8*>(eb + (size_t)row * KD + k0);
    }
#pragma unroll
    for (int rt = 0; rt < 8; ++rt)
#pragma unroll
      for (int ct = 0; ct < 4; ++ct)
        acc[rt][ct] = __builtin_amdgcn_mfma_f32_16x16x32_bf16(a[rt], b[ct], acc[rt][ct], 0, 0, 0);
  }

  // ---- epilogue: colnorm + transform + per-row sums into LDS ----
  const float t = tval[0];
#pragma unroll 1
  for (int rt = 0; rt < 8; ++rt) {
#pragma unroll
    for (int rg = 0; rg < 4; ++rg) {
      const int row = rbase + rt * 16 + q * 4 + rg;
      const float ctm = ctmA[row];
      const float fin = finA[row];
      const int   lab = label[row];
      float se = 0.f, sl = 0.f;
#pragma unroll
      for (int ct = 0; ct < 4; ++ct) {
        const int cg = c0 + ct * 16 + cl;
        if (cg < NCLS) {
          float cosv = acc[rt][ct][rg] * invnS[ct * 16 + cl];
          cosv = fminf(1.f, fmaxf(-1.f, cosv));
          float logit = (cosv > ctm) ? cosv * (t + cosv) : cosv;
          if (cg == lab) logit = fin;
          float x = S_SCALE * logit;
          se += __expf(x);
          sl += x;
        }
      }
#pragma unroll
      for (int m = 1; m < 16; m <<= 1) {
        se += __shfl_xor(se, m, 64);
        sl += __shfl_xor(sl, m, 64);
      }
      if (cl == 0) { sE[row] = se; sL[row] = sl; }
    }
  }
  __syncthreads();

  // ---- block-contiguous store: 4 KB float2 per block, written once --------
  {
    float2* dst = part + (size_t)blockIdx.x * 512;
    dst[tid]       = make_float2(sE[tid],       sL[tid]);
    dst[tid + 256] = make_float2(sE[tid + 256], sL[tid + 256]);
  }
}

// ---- K3a: stage-1 reduce over strips (coalesced) ---------------------------
__global__ void k_reduce1(const float2* __restrict__ part, float2* __restrict__ part2) {
  const int j = blockIdx.x;            // 0..63
  const int r = threadIdx.x;           // 0..511
  const int i0 = j * R1C;
  const int i1 = (i0 + R1C < NB) ? (i0 + R1C) : NB;
  float se = 0.f, sl = 0.f;
  for (int i = i0; i < i1; ++i) {
    float2 p = part[(size_t)i * 512 + r];
    se += p.x; sl += p.y;
  }
  part2[(size_t)j * 512 + r] = make_float2(se, sl);
}

// ---- K3b: stage-2 reduce + final loss (single block) -----------------------
__global__ void k_loss(const float2* __restrict__ part2, const float* __restrict__ finA,
                       float* __restrict__ out) {
  __shared__ float red[512];
  const int r = threadIdx.x;           // 0..511
  float se = 0.f, sl = 0.f;
#pragma unroll 4
  for (int j = 0; j < R1B; ++j) {
    float2 p = part2[(size_t)j * 512 + r];
    se += p.x; sl += p.y;
  }
  float lse = logf(se);                // no max-shift: se < 1e34
  float nll = lse - S_SCALE * finA[r];
  float sm  = lse - sl * (1.f / (float)NCLS);
  red[r] = 0.9f * nll + 0.1f * sm;
  __syncthreads();
  for (int s = 256; s > 0; s >>= 1) {
    if (r < s) red[r] += red[r + s];
    __syncthreads();
  }
  if (r == 0) out[0] = red[0] * (1.f / 512.f);
}

extern "C" void kernel_launch(void* const* d_in, const int* in_sizes, int n_in,
                              void* d_out, int out_size, void* d_ws, size_t ws_size,
                              hipStream_t stream) {
  (void)in_sizes; (void)n_in; (void)out_size; (void)ws_size;
  const float* emb = (const float*)d_in[0];
  const float* w   = (const float*)d_in[1];
  const int*   lab = (const int*)d_in[2];
  float* out = (float*)d_out;

  char* ws = (char*)d_ws;
  unsigned short* eb = (unsigned short*)ws;                       // 512 KB
  float* tlA   = (float*)(ws + 524288);
  float* ctmA  = tlA  + 512;
  float* finA  = ctmA + 512;
  float* tval  = finA + 512;
  float2* part  = (float2*)(ws + 524288 + 8192);                  // NB*512*8 = 6.4 MB
  float2* part2 = part + (size_t)NB * 512;                        // 64*512*8 = 256 KB

  hipLaunchKernelGGL(k0_norm_target, dim3(512), dim3(64), 0, stream, emb, w, lab, eb, tlA);
  hipLaunchKernelGGL(k_prep,    dim3(1),   dim3(512), 0, stream, tlA, ctmA, finA, tval);
  hipLaunchKernelGGL(k_gemm,    dim3(NB),  dim3(256), 0, stream,
                     w, eb, lab, ctmA, finA, tval, part);
  hipLaunchKernelGGL(k_reduce1, dim3(R1B), dim3(512), 0, stream, part, part2);
  hipLaunchKernelGGL(k_loss,    dim3(1),   dim3(512), 0, stream, part2, finA, out);
}

// Round 2
// 448.360 us; speedup vs baseline: 1.2777x; 1.2777x over previous
//
#include <hip/hip_runtime.h>

#define KD    512
#define NCLS  100000
#define BC    64
#define NB    ((NCLS + BC - 1) / BC)   // 1563
#define R1B   64                       // stage-1 reduce blocks
#define R1C   25                       // strips per stage-1 block (64*25 >= 1563)
#define S_SCALE 64.0f
#define COS_M   0.87758256189037276f
#define SIN_M   0.47942553860420301f
#define THRESH (-0.87758256189037276f)
#define MM_C    0.23971276930210151f

typedef __attribute__((ext_vector_type(8))) short short8;
typedef __attribute__((ext_vector_type(4))) float f32x4;

union Pack8 { unsigned short u[8]; uint4 v; };

__device__ __forceinline__ unsigned short f2bf(float x) {
  unsigned int u = __float_as_uint(x);
  u += 0x7fffu + ((u >> 16) & 1u);   // round-to-nearest-even
  return (unsigned short)(u >> 16);
}

// ---- K0: fused row-normalize(e) -> eb bf16, plus per-row target logit ------
__global__ void k0_norm_target(const float* __restrict__ emb, const float* __restrict__ w,
                               const int* __restrict__ label,
                               unsigned short* __restrict__ eb, float* __restrict__ tlA) {
  int r = blockIdx.x;
  int l = threadIdx.x;                 // 64 lanes, 8 elems each
  const float* src = emb + (size_t)r * KD + l * 8;
  float v[8];
  float ss = 0.f;
#pragma unroll
  for (int j = 0; j < 8; ++j) { v[j] = src[j]; ss += v[j] * v[j]; }
#pragma unroll
  for (int m = 1; m < 64; m <<= 1) ss += __shfl_xor(ss, m, 64);
  float rn = rsqrtf(ss);
  Pack8 p;
#pragma unroll
  for (int j = 0; j < 8; ++j) {
    float x = v[j] * rn;
    v[j] = x;                          // normalized fp32 kept in regs
    p.u[j] = f2bf(x);
  }
  *reinterpret_cast<uint4*>(eb + (size_t)r * KD + l * 8) = p.v;

  // target-column dot + its own norm (fp32 path, matches reference gather)
  int lab = label[r];
  float wv[8];
#pragma unroll
  for (int j = 0; j < 8; ++j) wv[j] = w[(size_t)(l * 8 + j) * NCLS + lab];
  float dot = 0.f, sq = 0.f;
#pragma unroll
  for (int j = 0; j < 8; ++j) { dot += v[j] * wv[j]; sq += wv[j] * wv[j]; }
#pragma unroll
  for (int m = 1; m < 64; m <<= 1) {
    dot += __shfl_xor(dot, m, 64);
    sq  += __shfl_xor(sq, m, 64);
  }
  if (l == 0) {
    float tl = dot * rsqrtf(sq);
    tlA[r] = fminf(1.f, fmaxf(-1.f, tl));
  }
}

// ---- K1: t = 0.01*mean(tl); per-row ctm / final ----------------------------
__global__ void k_prep(const float* __restrict__ tlA, float* __restrict__ ctmA,
                       float* __restrict__ finA, float* __restrict__ tval) {
  __shared__ float red[512];
  int i = threadIdx.x;
  float tl = tlA[i];
  red[i] = tl;
  __syncthreads();
  for (int s = 256; s > 0; s >>= 1) {
    if (i < s) red[i] += red[i + s];
    __syncthreads();
  }
  float st = sqrtf(fmaxf(0.f, 1.f - tl * tl));
  float ctm = tl * COS_M - st * SIN_M;
  ctmA[i] = ctm;
  finA[i] = (tl > THRESH) ? ctm : (tl - MM_C);
  if (i == 0) tval[0] = 0.01f * red[0] * (1.f / 512.f);
}

// ---- K2: bf16 MFMA GEMM (raw w) + epilogue colnorm + row partial sums ------
// Block: 512 rows x 64 cols, K=512. Staging coalesced along c (col = lane),
// two-phase with a binding sched_barrier so all 64 loads of a phase are in
// flight before any pack consumes them. w loads are nontemporal.
// LDS B-tile [c][k] swizzled: granule G = c*64 + ((k>>3) ^ (c&7)), 8 bf16/granule.
// EPILOGUE IS FULLY UNROLLED: acc[][] must only ever see compile-time-constant
// indices, else the whole accumulator is demoted to scratch (rule #20; this
// was ~400 MB of phantom HBM writes and a 5x slowdown in the R1 profile).
__global__ __launch_bounds__(256, 2)
void k_gemm(const float* __restrict__ w, const unsigned short* __restrict__ eb,
            const int* __restrict__ label, const float* __restrict__ ctmA,
            const float* __restrict__ finA, const float* __restrict__ tval,
            float2* __restrict__ part) {
  __shared__ __align__(16) unsigned short Bs[BC * KD];   // 64 KB
  __shared__ float ssW[4][BC];
  __shared__ float invnS[BC];
  __shared__ float sE[512];
  __shared__ float sL[512];
  const int tid = threadIdx.x;
  const int wv = tid >> 6;             // wave 0..3
  const int l  = tid & 63;
  const int c0 = blockIdx.x * BC;

  // ---- staging: col = lane; wave wv covers k in {wv*8 + o*32 + j} ----------
  {
    const int c = l;
    const int cgc = (c0 + c < NCLS) ? (c0 + c) : (NCLS - 1);   // clamp, no OOB
    const float* wp = w + cgc;
    float ss = 0.f;
#pragma unroll 1
    for (int ph = 0; ph < 2; ++ph) {
      float vb[8][8];
      // phase issue: 64 independent nontemporal loads, kept together by fence
#pragma unroll
      for (int b = 0; b < 8; ++b) {
        const int kb = wv * 8 + (ph * 8 + b) * 32;
#pragma unroll
        for (int j = 0; j < 8; ++j)
          vb[b][j] = __builtin_nontemporal_load(&wp[(size_t)(kb + j) * NCLS]);
      }
      __builtin_amdgcn_sched_barrier(0);   // nothing crosses: 64 loads stay in flight
      // phase consume: pack + swizzled ds_write_b128
#pragma unroll
      for (int b = 0; b < 8; ++b) {
        const int kb = wv * 8 + (ph * 8 + b) * 32;
        Pack8 p;
#pragma unroll
        for (int j = 0; j < 8; ++j) {
          float x = vb[b][j];
          ss += x * x;
          p.u[j] = f2bf(x);
        }
        const int G = c * 64 + ((kb >> 3) ^ (c & 7));
        *reinterpret_cast<uint4*>(&Bs[G * 8]) = p.v;
      }
    }
    ssW[wv][c] = ss;
  }
  __syncthreads();
  if (tid < BC) {
    float s = ssW[0][tid] + ssW[1][tid] + ssW[2][tid] + ssW[3][tid];
    invnS[tid] = (s > 0.f) ? rsqrtf(s) : 0.f;
  }
  __syncthreads();

  // ---- MFMA main loop: wave tile = 128 rows x 64 cols ----
  const int q  = l >> 4;
  const int cl = l & 15;
  const int rbase = wv * 128;
  f32x4 acc[8][4] = {};

#pragma unroll 1
  for (int s = 0; s < 16; ++s) {
    const int k0 = s * 32 + q * 8;
    short8 a[8], b[4];
#pragma unroll
    for (int ct = 0; ct < 4; ++ct) {
      int c = ct * 16 + cl;
      int G = c * 64 + ((k0 >> 3) ^ (c & 7));
      b[ct] = *reinterpret_cast<const short8*>(&Bs[G * 8]);
    }
#pragma unroll
    for (int rt = 0; rt < 8; ++rt) {
      int row = rbase + rt * 16 + cl;
      a[rt] = *reinterpret_cast<const short8*>(eb + (size_t)row * KD + k0);
    }
#pragma unroll
    for (int rt = 0; rt < 8; ++rt)
#pragma unroll
      for (int ct = 0; ct < 4; ++ct)
        acc[rt][ct] = __builtin_amdgcn_mfma_f32_16x16x32_bf16(a[rt], b[ct], acc[rt][ct], 0, 0, 0);
  }

  // ---- epilogue: colnorm + transform + per-row sums into LDS ----
  // FULLY unrolled: every acc index is a compile-time constant.
  const float t = tval[0];
#pragma unroll
  for (int rt = 0; rt < 8; ++rt) {
#pragma unroll
    for (int rg = 0; rg < 4; ++rg) {
      const int row = rbase + rt * 16 + q * 4 + rg;
      const float ctm = ctmA[row];
      const float fin = finA[row];
      const int   lab = label[row];
      float se = 0.f, sl = 0.f;
#pragma unroll
      for (int ct = 0; ct < 4; ++ct) {
        const int cg = c0 + ct * 16 + cl;
        if (cg < NCLS) {
          float cosv = acc[rt][ct][rg] * invnS[ct * 16 + cl];
          cosv = fminf(1.f, fmaxf(-1.f, cosv));
          float logit = (cosv > ctm) ? cosv * (t + cosv) : cosv;
          if (cg == lab) logit = fin;
          float x = S_SCALE * logit;
          se += __expf(x);
          sl += x;
        }
      }
#pragma unroll
      for (int m = 1; m < 16; m <<= 1) {
        se += __shfl_xor(se, m, 64);
        sl += __shfl_xor(sl, m, 64);
      }
      if (cl == 0) { sE[row] = se; sL[row] = sl; }
    }
  }
  __syncthreads();

  // ---- block-contiguous store: 4 KB float2 per block, written once --------
  {
    float2* dst = part + (size_t)blockIdx.x * 512;
    dst[tid]       = make_float2(sE[tid],       sL[tid]);
    dst[tid + 256] = make_float2(sE[tid + 256], sL[tid + 256]);
  }
}

// ---- K3a: stage-1 reduce over strips (coalesced) ---------------------------
__global__ void k_reduce1(const float2* __restrict__ part, float2* __restrict__ part2) {
  const int j = blockIdx.x;            // 0..63
  const int r = threadIdx.x;           // 0..511
  const int i0 = j * R1C;
  const int i1 = (i0 + R1C < NB) ? (i0 + R1C) : NB;
  float se = 0.f, sl = 0.f;
  for (int i = i0; i < i1; ++i) {
    float2 p = part[(size_t)i * 512 + r];
    se += p.x; sl += p.y;
  }
  part2[(size_t)j * 512 + r] = make_float2(se, sl);
}

// ---- K3b: stage-2 reduce + final loss (single block) -----------------------
__global__ void k_loss(const float2* __restrict__ part2, const float* __restrict__ finA,
                       float* __restrict__ out) {
  __shared__ float red[512];
  const int r = threadIdx.x;           // 0..511
  float se = 0.f, sl = 0.f;
#pragma unroll 4
  for (int j = 0; j < R1B; ++j) {
    float2 p = part2[(size_t)j * 512 + r];
    se += p.x; sl += p.y;
  }
  float lse = logf(se);                // no max-shift: se < 1e34
  float nll = lse - S_SCALE * finA[r];
  float sm  = lse - sl * (1.f / (float)NCLS);
  red[r] = 0.9f * nll + 0.1f * sm;
  __syncthreads();
  for (int s = 256; s > 0; s >>= 1) {
    if (r < s) red[r] += red[r + s];
    __syncthreads();
  }
  if (r == 0) out[0] = red[0] * (1.f / 512.f);
}

extern "C" void kernel_launch(void* const* d_in, const int* in_sizes, int n_in,
                              void* d_out, int out_size, void* d_ws, size_t ws_size,
                              hipStream_t stream) {
  (void)in_sizes; (void)n_in; (void)out_size; (void)ws_size;
  const float* emb = (const float*)d_in[0];
  const float* w   = (const float*)d_in[1];
  const int*   lab = (const int*)d_in[2];
  float* out = (float*)d_out;

  char* ws = (char*)d_ws;
  unsigned short* eb = (unsigned short*)ws;                       // 512 KB
  float* tlA   = (float*)(ws + 524288);
  float* ctmA  = tlA  + 512;
  float* finA  = ctmA + 512;
  float* tval  = finA + 512;
  float2* part  = (float2*)(ws + 524288 + 8192);                  // NB*512*8 = 6.4 MB
  float2* part2 = part + (size_t)NB * 512;                        // 64*512*8 = 256 KB

  hipLaunchKernelGGL(k0_norm_target, dim3(512), dim3(64), 0, stream, emb, w, lab, eb, tlA);
  hipLaunchKernelGGL(k_prep,    dim3(1),   dim3(512), 0, stream, tlA, ctmA, finA, tval);
  hipLaunchKernelGGL(k_gemm,    dim3(NB),  dim3(256), 0, stream,
                     w, eb, lab, ctmA, finA, tval, part);
  hipLaunchKernelGGL(k_reduce1, dim3(R1B), dim3(512), 0, stream, part, part2);
  hipLaunchKernelGGL(k_loss,    dim3(1),   dim3(512), 0, stream, part2, finA, out);
}